// Round 9
// baseline (140.438 us; speedup 1.0000x reference)
//
#include <hip/hip_runtime.h>

#define NB 32
#define NC 256
#define HW 4096   // 64*64
#define RDIM 16   // C/R = 256/16
#define KTOP 128

typedef float v4f __attribute__((ext_vector_type(4)));

// ---------------------------------------------------------------------------
// Single fused kernel, 1024 blocks x 256 threads (exactly 4 blocks/CU, whole
// grid co-resident at VGPR<=128 -> per-batch wait cannot deadlock).
// Block g, batch b=g>>5, slot=g&31:
//   Phase 1: pool 8 planes of batch b (2 per wave), PLAIN stores to y,
//            then ONE release fetch_add on cnt[b] (flushes this XCD's L2).
//   Wait:    relaxed polls of cnt[b] (no cache invalidation!) + s_sleep,
//            then ONE acquire fence when cnt[b]==32.
//   Phase 2: SE-MLP + sigmoid + top-k(128) in LDS, gather 4 planes
//            (1 per wave) from L3-resident x, NT stores to out.
// ---------------------------------------------------------------------------
__global__ __launch_bounds__(256, 4) void ca_fused_relaxed_kernel(
    const float* __restrict__ x, float* __restrict__ y, int* __restrict__ cnt,
    const float* __restrict__ w1, const float* __restrict__ b1,
    const float* __restrict__ w2, const float* __restrict__ b2,
    float* __restrict__ out) {
    const int g    = blockIdx.x;                        // 0..1023
    const int b    = g >> 5;                            // batch
    const int slot = g & 31;
    const int t    = threadIdx.x;
    const int wid  = t >> 6, lane = t & 63;

    // ---- Phase 1: pool 8 planes, 2 per wave, interleaved loads ----
    const int p0 = b * NC + slot * 8 + wid * 2;         // global plane index
    {
        const v4f* __restrict__ x0 = (const v4f*)(x + (size_t)p0 * HW);
        const v4f* __restrict__ x1 = (const v4f*)(x + (size_t)(p0 + 1) * HW);
        float s0 = 0.f, s1 = 0.f;
#pragma unroll
        for (int i = 0; i < 16; ++i) {
            v4f a = x0[lane + i * 64];
            v4f c = x1[lane + i * 64];
            s0 += (a.x + a.y) + (a.z + a.w);
            s1 += (c.x + c.y) + (c.z + c.w);
        }
#pragma unroll
        for (int off = 32; off > 0; off >>= 1) {
            s0 += __shfl_down(s0, off);
            s1 += __shfl_down(s1, off);
        }
        if (lane == 0) {                                // plain stores
            y[p0]     = s0 * (1.0f / HW);
            y[p0 + 1] = s1 * (1.0f / HW);
        }
    }
    __syncthreads();
    if (t == 0) {
        // ONE release op per block: orders/flushes the y stores agent-wide.
        __hip_atomic_fetch_add(&cnt[b], 1, __ATOMIC_RELEASE,
                               __HIP_MEMORY_SCOPE_AGENT);
        // ---- Wait: relaxed polls only (no per-poll cache invalidation) ----
        int it = 0;
        while (__hip_atomic_load(&cnt[b], __ATOMIC_RELAXED,
                                 __HIP_MEMORY_SCOPE_AGENT) < 32) {
            __builtin_amdgcn_s_sleep(32);
            if (++it > 200000) break;                   // ~0.2s cap, no hang
        }
        // ONE acquire fence: invalidate stale L1/L2 lines once.
        __builtin_amdgcn_fence(__ATOMIC_ACQUIRE, "agent");
    }
    __syncthreads();                                    // publish to block

    // ---- Phase 2a: SE-MLP + sigmoid + top-k in LDS ----
    __shared__ float ych[NC];
    __shared__ float hsh[RDIM];
    __shared__ float attn[NC];
    __shared__ unsigned long long masks[4];
    __shared__ int   sidx[KTOP];
    __shared__ float saw[KTOP];

    ych[t] = y[b * NC + t];                             // plain loads
    __syncthreads();

    const int r = t >> 4;
    const int j = t & 15;
    float partial = 0.f;
#pragma unroll
    for (int k = 0; k < 16; ++k) {
        const int c = j * 16 + k;
        partial += ych[c] * w1[r * NC + c];
    }
#pragma unroll
    for (int m = 8; m > 0; m >>= 1) partial += __shfl_xor(partial, m, 16);
    if (j == 0) hsh[r] = fmaxf(partial + b1[r], 0.f);
    __syncthreads();

    float z = b2[t];
#pragma unroll
    for (int rr = 0; rr < RDIM; ++rr) z += hsh[rr] * w2[t * RDIM + rr];
    const float v = 1.0f / (1.0f + __expf(-z));
    attn[t] = v;
    __syncthreads();

    // rank (strict order, tie -> lower index wins == jax.lax.top_k).
    int rank = 0;
#pragma unroll 4
    for (int c = 0; c < NC; ++c) {
        const float o = attn[c];
        rank += (o > v) || (o == v && c < t);
    }
    const bool s = (rank < KTOP);

    // ballot-based compaction into LDS (ascending channel index).
    const unsigned long long m = __ballot(s);
    if (lane == 0) masks[wid] = m;
    __syncthreads();
    if (s) {
        int pos = __popcll(m & ((lane == 63) ? 0x7FFFFFFFFFFFFFFFull
                                             : ((1ull << lane) - 1ull)));
        for (int w = 0; w < 4; ++w) pos += (w < wid) ? __popcll(masks[w]) : 0;
        sidx[pos] = t;
        saw[pos]  = v;
    }
    __syncthreads();

    // ---- Phase 2b: gather + scale, ONE output plane per wave ----
    const int k = slot * 4 + wid;                       // 0..KTOP-1
    const int c = sidx[k];
    const float w = saw[k];
    const v4f* __restrict__ xin = (const v4f*)(x + ((size_t)b * NC + c) * HW);
    v4f* __restrict__ o = (v4f*)(out + ((size_t)b * KTOP + k) * HW);
#pragma unroll
    for (int i = 0; i < 16; ++i) {
        v4f vv = xin[lane + i * 64];
        v4f rr = vv * w;
        __builtin_nontemporal_store(rr, &o[lane + i * 64]);
    }
}

// ---------------------------------------------------------------------------
extern "C" void kernel_launch(void* const* d_in, const int* in_sizes, int n_in,
                              void* d_out, int out_size, void* d_ws, size_t ws_size,
                              hipStream_t stream) {
    const float* x  = (const float*)d_in[0];
    const float* w1 = (const float*)d_in[1];
    const float* b1 = (const float*)d_in[2];
    const float* w2 = (const float*)d_in[3];
    const float* b2 = (const float*)d_in[4];
    float* out = (float*)d_out;

    float* y   = (float*)d_ws;                          // y[NB*NC]
    int*   cnt = (int*)(y + NB * NC);                   // cnt[NB]

    // counters must be 0 at the start of every call (ws is not re-poisoned
    // between replays); async memset is graph-capture-safe (verified R6).
    (void)hipMemsetAsync(cnt, 0, NB * sizeof(int), stream);

    ca_fused_relaxed_kernel<<<NB * NC / 8, 256, 0, stream>>>(
        x, y, cnt, w1, b1, w2, b2, out);
}

// Round 10
// 131.399 us; speedup vs baseline: 1.0688x; 1.0688x over previous
//
#include <hip/hip_runtime.h>

#define NB 32
#define NC 256
#define HW 4096   // 64*64
#define RDIM 16   // C/R = 256/16
#define KTOP 128

typedef float v4f __attribute__((ext_vector_type(4)));

// ---------------------------------------------------------------------------
// Kernel 1: pool + tail-sek. 2048 blocks x 256 threads, 1 plane per wave.
// After pooling, each block does ONE acq_rel fetch_add on cnt[batch]; the
// block that sees prev==63 (last of its batch -- nobody waits on it, no
// spinning anywhere) issues one acquire fence and computes the SE-MLP +
// sigmoid + top-k for its batch, writing idx/aw to workspace. The kernel
// boundary then publishes everything to the gather kernel.
// ---------------------------------------------------------------------------
__global__ __launch_bounds__(256) void pool_sek_kernel(
    const float* __restrict__ x, float* __restrict__ y, int* __restrict__ cnt,
    const float* __restrict__ w1, const float* __restrict__ b1,
    const float* __restrict__ w2, const float* __restrict__ b2,
    int* __restrict__ idx_out, float* __restrict__ aw_out) {
    const int blk = blockIdx.x;                         // 0..2047
    const int b   = blk >> 6;                           // 64 blocks / batch
    const int t   = threadIdx.x;
    const int wid = t >> 6, lane = t & 63;

    // ---- pool: one plane per wave ----
    const int plane = blk * 4 + wid;                    // = b*NC + c
    {
        const v4f* __restrict__ xin = (const v4f*)(x + (size_t)plane * HW);
        float s = 0.f;
#pragma unroll
        for (int i = 0; i < 16; ++i) {                  // 1024 v4 / 64 lanes
            v4f v = xin[lane + i * 64];
            s += (v.x + v.y) + (v.z + v.w);
        }
#pragma unroll
        for (int off = 32; off > 0; off >>= 1) s += __shfl_down(s, off);
        if (lane == 0) y[plane] = s * (1.0f / HW);
    }
    __syncthreads();                                    // block's y stores done

    // ---- last-block election (no waiting, no polls) ----
    __shared__ int amLast;
    if (t == 0) {
        const int prev = __hip_atomic_fetch_add(&cnt[b], 1, __ATOMIC_ACQ_REL,
                                                __HIP_MEMORY_SCOPE_AGENT);
        amLast = (prev == 63);
    }
    __syncthreads();
    if (!amLast) return;

    // one acquire fence: make all 64 blocks' y stores visible to this block
    __builtin_amdgcn_fence(__ATOMIC_ACQUIRE, "agent");

    // ---- sek: SE-MLP + sigmoid + top-k(128) for batch b ----
    __shared__ float ych[NC];
    __shared__ float hsh[RDIM];
    __shared__ float attn[NC];
    __shared__ unsigned long long masks[4];

    ych[t] = y[b * NC + t];
    __syncthreads();

    const int r = t >> 4;
    const int j = t & 15;
    float partial = 0.f;
#pragma unroll
    for (int k = 0; k < 16; ++k) {
        const int c = j * 16 + k;
        partial += ych[c] * w1[r * NC + c];
    }
#pragma unroll
    for (int m = 8; m > 0; m >>= 1) partial += __shfl_xor(partial, m, 16);
    if (j == 0) hsh[r] = fmaxf(partial + b1[r], 0.f);
    __syncthreads();

    float z = b2[t];
#pragma unroll
    for (int rr = 0; rr < RDIM; ++rr) z += hsh[rr] * w2[t * RDIM + rr];
    const float v = 1.0f / (1.0f + __expf(-z));
    attn[t] = v;
    __syncthreads();

    // rank (strict order, tie -> lower index wins == jax.lax.top_k).
    int rank = 0;
#pragma unroll 8
    for (int c = 0; c < NC; ++c) {
        const float o = attn[c];
        rank += (o > v) || (o == v && c < t);
    }
    const bool s = (rank < KTOP);

    // ballot-based compaction (ascending channel index) -> global idx/aw.
    const unsigned long long m = __ballot(s);
    if (lane == 0) masks[wid] = m;
    __syncthreads();
    if (s) {
        int pos = __popcll(m & ((lane == 63) ? 0x7FFFFFFFFFFFFFFFull
                                             : ((1ull << lane) - 1ull)));
        for (int w = 0; w < 4; ++w) pos += (w < wid) ? __popcll(masks[w]) : 0;
        idx_out[b * KTOP + pos] = t;
        aw_out[b * KTOP + pos]  = v;
    }
}

// ---------------------------------------------------------------------------
// Kernel 2: pure gather+scale stream. 1024 blocks, one output plane per
// wave; 2 scalar loads then 16 KB copy, NT stores. Zero compute bubble.
// ---------------------------------------------------------------------------
__global__ __launch_bounds__(256) void gather_kernel(
    const float* __restrict__ x,
    const int* __restrict__ idx, const float* __restrict__ aw,
    float* __restrict__ out) {
    const int wid  = threadIdx.x >> 6;
    const int lane = threadIdx.x & 63;
    const int p = blockIdx.x * 4 + wid;                 // 0 .. NB*KTOP-1
    const int b = p >> 7;                               // /128
    const int c = idx[p];
    const float w = aw[p];
    const v4f* __restrict__ xin = (const v4f*)(x + ((size_t)b * NC + c) * HW);
    v4f* __restrict__ o = (v4f*)(out + (size_t)p * HW);
#pragma unroll
    for (int i = 0; i < 16; ++i) {
        v4f vv = xin[lane + i * 64];
        v4f rr = vv * w;
        __builtin_nontemporal_store(rr, &o[lane + i * 64]);
    }
}

// ---------------------------------------------------------------------------
extern "C" void kernel_launch(void* const* d_in, const int* in_sizes, int n_in,
                              void* d_out, int out_size, void* d_ws, size_t ws_size,
                              hipStream_t stream) {
    const float* x  = (const float*)d_in[0];
    const float* w1 = (const float*)d_in[1];
    const float* b1 = (const float*)d_in[2];
    const float* w2 = (const float*)d_in[3];
    const float* b2 = (const float*)d_in[4];
    float* out = (float*)d_out;

    // ws layout: y[NB*NC] f32 | cnt[NB] i32 | idx[NB*KTOP] i32 | aw[NB*KTOP]
    float* y   = (float*)d_ws;
    int*   cnt = (int*)(y + NB * NC);
    int*   idx = cnt + NB;
    float* aw  = (float*)(idx + NB * KTOP);

    // cnt must be zero at the start of every call (graph-capture-safe,
    // verified in R6/R9).
    (void)hipMemsetAsync(cnt, 0, NB * sizeof(int), stream);

    pool_sek_kernel<<<NB * NC / 4, 256, 0, stream>>>(
        x, y, cnt, w1, b1, w2, b2, idx, aw);
    gather_kernel<<<NB * KTOP / 4, 256, 0, stream>>>(x, idx, aw, out);
}

// Round 11
// 114.478 us; speedup vs baseline: 1.2268x; 1.1478x over previous
//
#include <hip/hip_runtime.h>

#define NB 32
#define NC 256
#define HW 4096   // 64*64
#define RDIM 16   // C/R = 256/16
#define KTOP 128
#define REPS 4    // diagnostic: idempotent repeats to surface in rocprof top-5

typedef float v4f __attribute__((ext_vector_type(4)));

// ---------------------------------------------------------------------------
// DIAGNOSTIC ROUND: exact R3 structure, each kernel body repeated REPS times
// (idempotent -- same values written each pass). Purpose: get per-kernel
// dur/FETCH/WRITE into the top-5 counter table (harness fills at ~75us
// otherwise hide our ~20us kernels). Per-pass metrics = reported / REPS.
// ---------------------------------------------------------------------------

// Kernel 1: global average pool, one wave per (b,c) plane. 2048 blocks.
__global__ __launch_bounds__(256) void pool_kernel_4x(
    const float* __restrict__ x, float* __restrict__ y) {
    const int wid  = threadIdx.x >> 6;
    const int lane = threadIdx.x & 63;
    const int plane = blockIdx.x * 4 + wid;             // 0 .. NB*NC-1
    const v4f* __restrict__ xin = (const v4f*)(x + (size_t)plane * HW);
#pragma unroll 1
    for (int rep = 0; rep < REPS; ++rep) {
        float s = 0.f;
#pragma unroll
        for (int i = 0; i < 16; ++i) {                  // 1024 v4 / 64 lanes
            v4f v = xin[lane + i * 64];
            s += (v.x + v.y) + (v.z + v.w);
        }
#pragma unroll
        for (int off = 32; off > 0; off >>= 1) s += __shfl_down(s, off);
        if (lane == 0) y[plane] = s * (1.0f / HW);
    }
}

// Kernel 2: fused SE-MLP + sigmoid + top-k(128) + gather/scale. 1024 blocks.
__global__ __launch_bounds__(256) void se_topk_gather_4x(
    const float* __restrict__ x, const float* __restrict__ y,
    const float* __restrict__ w1, const float* __restrict__ b1,
    const float* __restrict__ w2, const float* __restrict__ b2,
    float* __restrict__ out) {
    const int blk = blockIdx.x;                         // 0..1023
    const int b   = blk >> 5;                           // 32 blocks / batch
    const int t   = threadIdx.x;
    const int wid = t >> 6, lane = t & 63;

    __shared__ float ych[NC];
    __shared__ float hsh[RDIM];
    __shared__ float attn[NC];
    __shared__ unsigned long long masks[4];
    __shared__ int   sidx[KTOP];
    __shared__ float saw[KTOP];

#pragma unroll 1
    for (int rep = 0; rep < REPS; ++rep) {
        __syncthreads();                                // separate passes

        ych[t] = y[b * NC + t];
        __syncthreads();

        const int r = t >> 4;
        const int j = t & 15;
        float partial = 0.f;
#pragma unroll
        for (int k = 0; k < 16; ++k) {
            const int c = j * 16 + k;
            partial += ych[c] * w1[r * NC + c];
        }
#pragma unroll
        for (int m = 8; m > 0; m >>= 1) partial += __shfl_xor(partial, m, 16);
        if (j == 0) hsh[r] = fmaxf(partial + b1[r], 0.f);
        __syncthreads();

        float z = b2[t];
#pragma unroll
        for (int rr = 0; rr < RDIM; ++rr) z += hsh[rr] * w2[t * RDIM + rr];
        const float v = 1.0f / (1.0f + __expf(-z));
        attn[t] = v;
        __syncthreads();

        // rank (strict order, tie -> lower index wins == jax.lax.top_k).
        int rank = 0;
#pragma unroll 4
        for (int c = 0; c < NC; ++c) {
            const float o = attn[c];
            rank += (o > v) || (o == v && c < t);
        }
        const bool s = (rank < KTOP);

        // ballot-based compaction into LDS (ascending channel index).
        const unsigned long long m = __ballot(s);
        if (lane == 0) masks[wid] = m;
        __syncthreads();
        if (s) {
            int pos = __popcll(m & ((lane == 63) ? 0x7FFFFFFFFFFFFFFFull
                                                 : ((1ull << lane) - 1ull)));
            for (int w = 0; w < 4; ++w) pos += (w < wid) ? __popcll(masks[w]) : 0;
            sidx[pos] = t;
            saw[pos]  = v;
        }
        __syncthreads();

        // gather + scale: one output plane per wave, NT stores.
        const int k = (blk & 31) * 4 + wid;             // 0..KTOP-1
        const int c = sidx[k];
        const float w = saw[k];
        const v4f* __restrict__ xin = (const v4f*)(x + ((size_t)b * NC + c) * HW);
        v4f* __restrict__ o = (v4f*)(out + ((size_t)b * KTOP + k) * HW);
#pragma unroll
        for (int i = 0; i < 16; ++i) {
            v4f vv = xin[lane + i * 64];
            v4f rr = vv * w;
            __builtin_nontemporal_store(rr, &o[lane + i * 64]);
        }
    }
}

// ---------------------------------------------------------------------------
extern "C" void kernel_launch(void* const* d_in, const int* in_sizes, int n_in,
                              void* d_out, int out_size, void* d_ws, size_t ws_size,
                              hipStream_t stream) {
    const float* x  = (const float*)d_in[0];
    const float* w1 = (const float*)d_in[1];
    const float* b1 = (const float*)d_in[2];
    const float* w2 = (const float*)d_in[3];
    const float* b2 = (const float*)d_in[4];
    float* out = (float*)d_out;
    float* y   = (float*)d_ws;                          // y[NB*NC]

    pool_kernel_4x<<<NB * NC / 4, 256, 0, stream>>>(x, y);
    se_topk_gather_4x<<<NB * KTOP / 4, 256, 0, stream>>>(
        x, y, w1, b1, w2, b2, out);
}